// Round 7
// baseline (178.941 us; speedup 1.0000x reference)
//
#include <hip/hip_runtime.h>
#include <hip/hip_bf16.h>
#include <math.h>

typedef _Float16 half8 __attribute__((ext_vector_type(8)));
typedef float f32x4 __attribute__((ext_vector_type(4)));

#define NE 500000
#define ND 128
#define NNODES 100000
#define NT ((NE + 63) / 64)          // 7813 tiles of 64 edges
#define TPB 8                        // tiles per block

// W1 [K=256][N=256] f32  ->  W1T [N=256][K=256] fp16 (k-contiguous rows)
__global__ void prep_w1t_kernel(const float* __restrict__ W1,
                                _Float16* __restrict__ W1T) {
    int i = blockIdx.x * blockDim.x + threadIdx.x;   // 0..65535
    int n = i >> 8, k = i & 255;
    W1T[n * 256 + k] = (_Float16)W1[k * 256 + n];
}

// z, z2 f32 -> fp16 mirrors (8 elems/thread)
__global__ __launch_bounds__(256) void prep_zh_kernel(
    const float* __restrict__ z, const float* __restrict__ z2,
    _Float16* __restrict__ zh, _Float16* __restrict__ z2h) {
    long t = (long)blockIdx.x * 256 + threadIdx.x;   // 0..3,199,999
    const float* src; _Float16* dst; long off;
    const long halfn = (long)NNODES * ND / 8;        // 1,600,000
    if (t < halfn) { src = z;  dst = zh;  off = t * 8; }
    else           { src = z2; dst = z2h; off = (t - halfn) * 8; }
    float4 a = *reinterpret_cast<const float4*>(src + off);
    float4 b = *reinterpret_cast<const float4*>(src + off + 4);
    half8 v;
    v[0] = (_Float16)a.x; v[1] = (_Float16)a.y;
    v[2] = (_Float16)a.z; v[3] = (_Float16)a.w;
    v[4] = (_Float16)b.x; v[5] = (_Float16)b.y;
    v[6] = (_Float16)b.z; v[7] = (_Float16)b.w;
    *reinterpret_cast<half8*>(dst + off) = v;
}

// DMA-staged kernel: gathers go global->LDS via global_load_lds (per-lane
// scattered SOURCE, linear LDS dest). Products formed at A-frag build time.
// Per-iteration vmem per wave is exactly {8 DMA, 1 idxload, [1 store]} so a
// counted vmcnt(10) at the tile boundary waits only the PREVIOUS tile's DMA.
__global__ __launch_bounds__(512, 1) void edge_mlp_dma(
    const _Float16* __restrict__ zh, const _Float16* __restrict__ z2h,
    const int* __restrict__ edge,
    const _Float16* __restrict__ w1t,
    const float* __restrict__ b1, const float* __restrict__ W2,
    const float* __restrict__ b2, float* __restrict__ out)
{
    __shared__ _Float16 rawS[2][64][256];   // 64 KB: src rows  [z | z2]
    __shared__ _Float16 rawD[2][64][256];   // 64 KB: dst rows  [z | z2]
    __shared__ float partials[4][64];       // 1 KB

    const int tid = threadIdx.x;
    const int lane = tid & 63;
    const int wv = tid >> 6;             // 0..7
    const int mi = wv >> 2;              // rows [mi*32, mi*32+32)
    const int ni = wv & 3;               // cols [ni*64, ni*64+64)
    const int l15 = lane & 15;
    const int l4 = lane >> 4;

    // DMA lane constants: 1KB instr = 2 edge-rows (512B each).
    const int dl5 = lane >> 5;           // which edge of the pair
    const int dcc = lane & 15;           // 16B chunk within the 128-elem sub-row
    const int dten = (lane >> 4) & 1;    // z vs z2 half
    const _Float16* dbase = dten ? z2h : zh;

    // ---- pipeline prologue part 1: start tile-t0 DMA ASAP ----
    const int t0 = blockIdx.x * TPB;
    const int tend = (t0 + TPB < NT) ? (t0 + TPB) : NT;

#define LOAD_IDX(TT, DST) do {                                               \
        int tt_ = (TT) < (NT - 1) ? (TT) : (NT - 1);                         \
        long e_ = (long)tt_ * 64 + wv * 8 + (lane & 7);                      \
        if (e_ >= NE) e_ = NE - 1;                                           \
        (DST) = edge[(((lane >> 3) & 1) ? (long)NE : 0L) + e_];              \
    } while (0)

#define ISSUE_DMA(IDXREG, BB) do {                                           \
        _Pragma("unroll")                                                    \
        for (int j = 0; j < 4; ++j) {                                        \
            int sl_ = 2 * j + dl5;                                           \
            int si_ = __shfl((IDXREG), sl_, 64);                             \
            int di_ = __shfl((IDXREG), 8 + sl_, 64);                         \
            int swz_ = (dcc ^ sl_) << 3;  /* inverse-swizzled source chunk */\
            const _Float16* gs_ = dbase + (long)si_ * ND + swz_;             \
            const _Float16* gd_ = dbase + (long)di_ * ND + swz_;             \
            __builtin_amdgcn_global_load_lds(                                \
                (const void*)gs_, (void*)&rawS[BB][wv * 8 + 2 * j][0], 16, 0, 0); \
            __builtin_amdgcn_global_load_lds(                                \
                (const void*)gd_, (void*)&rawD[BB][wv * 8 + 2 * j][0], 16, 0, 0); \
        }                                                                    \
    } while (0)

    int idx_cur, idx_new;
    {
        int idx0;
        LOAD_IDX(t0, idx0);              // vm: 1
        ISSUE_DMA(idx0, 0);              // vm: 8  (DMA of tile t0 -> buf 0)
        LOAD_IDX(t0 + 1, idx_cur);       // vm: 1  (indices for tile t0+1)
    }

    // ---- prologue part 2: block-invariant registers ----
    half8 breg[4][8];
#pragma unroll
    for (int nf = 0; nf < 4; ++nf)
#pragma unroll
        for (int ks = 0; ks < 8; ++ks)
            breg[nf][ks] = *reinterpret_cast<const half8*>(
                w1t + (long)(ni * 64 + nf * 16 + l15) * 256 + ks * 32 + l4 * 8);

    float b1v[4], w2v[4];
#pragma unroll
    for (int nf = 0; nf < 4; ++nf) {
        int col = ni * 64 + nf * 16 + l15;
        b1v[nf] = b1[col];
        w2v[nf] = W2[col];
    }
    const float bias2 = b2[0];

    for (int t = t0; t < tend; ++t) {
        const int cur = (t - t0) & 1, nxt = cur ^ 1;

        // 1. issue DMA(t+1) + idxload(t+2): stay in flight across MFMA(t)
        ISSUE_DMA(idx_cur, nxt);         // vm: 8
        LOAD_IDX(t + 2, idx_new);        // vm: 1

        // 2. counted wait: all but the 10 newest vmem ops done == DMA(t) done
        asm volatile("s_waitcnt vmcnt(10)" ::: "memory");
        __builtin_amdgcn_s_barrier();    // all waves' DMA(t) published
        __builtin_amdgcn_sched_barrier(0);

        // 3. MFMA over raw[cur]: A = (zs*zd) built in-regs from the two tiles
        f32x4 acc[2][4];
#pragma unroll
        for (int mf = 0; mf < 2; ++mf)
#pragma unroll
            for (int nf = 0; nf < 4; ++nf)
                acc[mf][nf] = (f32x4){0.f, 0.f, 0.f, 0.f};

        const _Float16* rs = &rawS[cur][0][0];
        const _Float16* rd = &rawD[cur][0][0];
#pragma unroll
        for (int ks = 0; ks < 8; ++ks) {
            const int c = ks * 4 + l4;                       // global 16B chunk
            const int slot = ((c & 15) ^ (l15 & 7)) | (c & 16);  // swizzled
            const int so = slot * 8;
#pragma unroll
            for (int mf = 0; mf < 2; ++mf) {
                int row = mi * 32 + mf * 16 + l15;
                int o = row * 256 + so;
                half8 aS = *reinterpret_cast<const half8*>(rs + o);
                half8 aD = *reinterpret_cast<const half8*>(rd + o);
                half8 a = aS * aD;                            // v_pk_mul_f16
#pragma unroll
                for (int nf = 0; nf < 4; ++nf)
                    acc[mf][nf] = __builtin_amdgcn_mfma_f32_16x16x32_f16(
                        a, breg[nf][ks], acc[mf][nf], 0, 0, 0);
            }
        }

        // 4. relu + dot(W2): 16-lane shuffle reduce -> partials
#pragma unroll
        for (int mf = 0; mf < 2; ++mf) {
            float s0 = 0.f, s1 = 0.f, s2 = 0.f, s3 = 0.f;
#pragma unroll
            for (int nf = 0; nf < 4; ++nf) {
                float h0 = fmaxf(acc[mf][nf][0] + b1v[nf], 0.f);
                float h1 = fmaxf(acc[mf][nf][1] + b1v[nf], 0.f);
                float h2 = fmaxf(acc[mf][nf][2] + b1v[nf], 0.f);
                float h3 = fmaxf(acc[mf][nf][3] + b1v[nf], 0.f);
                s0 += h0 * w2v[nf]; s1 += h1 * w2v[nf];
                s2 += h2 * w2v[nf]; s3 += h3 * w2v[nf];
            }
#pragma unroll
            for (int mask = 1; mask < 16; mask <<= 1) {
                s0 += __shfl_xor(s0, mask, 64);
                s1 += __shfl_xor(s1, mask, 64);
                s2 += __shfl_xor(s2, mask, 64);
                s3 += __shfl_xor(s3, mask, 64);
            }
            if (l15 == 0) {
                int rb = mi * 32 + mf * 16 + l4 * 4;
                partials[ni][rb + 0] = s0;
                partials[ni][rb + 1] = s1;
                partials[ni][rb + 2] = s2;
                partials[ni][rb + 3] = s3;
            }
        }
        asm volatile("s_waitcnt lgkmcnt(0)" ::: "memory");
        __builtin_amdgcn_s_barrier();    // partials published
        __builtin_amdgcn_sched_barrier(0);

        // 5. combine + sigmoid + store: each wave stores its own 8 edges
        if (lane < 8) {
            int r = wv * 8 + lane;
            float p = partials[0][r] + partials[1][r]
                    + partials[2][r] + partials[3][r] + bias2;
            long e = (long)t * 64 + r;
            if (e < NE) out[e] = 1.0f / (1.0f + expf(-p));   // vm: 1
        }
        idx_cur = idx_new;
    }
#undef LOAD_IDX
#undef ISSUE_DMA
}

// Fallback (ws too small for mirrors): f32 gather, fp16 x, fp16 w1t (128 KB ws)
__global__ __launch_bounds__(256) void edge_mlp_f32(
    const float* __restrict__ z, const float* __restrict__ z2,
    const int* __restrict__ edge,
    const _Float16* __restrict__ w1t,
    const float* __restrict__ b1, const float* __restrict__ W2,
    const float* __restrict__ b2, float* __restrict__ out)
{
    __shared__ _Float16 xs[64 * 256];
    __shared__ float partials[4][64];
    const int tid = threadIdx.x, lane = tid & 63, wv = tid >> 6;
    const int l15 = lane & 15, l4 = lane >> 4;
    const long eb0 = (long)blockIdx.x * 64;
    {
        const int hz = lane >> 5, c4 = lane & 31;
        const float* base = hz ? z2 : z;
        for (int i = 0; i < 16; ++i) {
            int el = (wv << 4) + i;
            long ee = eb0 + el; if (ee >= NE) ee = NE - 1;
            long s = edge[ee], d = edge[NE + ee];
            float4 a = *reinterpret_cast<const float4*>(base + s * ND + (c4 << 2));
            float4 b = *reinterpret_cast<const float4*>(base + d * ND + (c4 << 2));
            _Float16 p[4] = {(_Float16)(a.x * b.x), (_Float16)(a.y * b.y),
                             (_Float16)(a.z * b.z), (_Float16)(a.w * b.w)};
            int col0 = (hz << 7) + (c4 << 2);
            int o = el * 256 + (col0 ^ ((el & 7) << 3));
            xs[o] = p[0]; xs[o + 1] = p[1]; xs[o + 2] = p[2]; xs[o + 3] = p[3];
        }
    }
    __syncthreads();
    f32x4 acc[4][4];
    for (int m = 0; m < 4; ++m) for (int n = 0; n < 4; ++n) acc[m][n] = (f32x4){0,0,0,0};
    const int ncol0 = wv * 64 + l15;
    for (int ks = 0; ks < 8; ++ks) {
        const int k0 = ks * 32 + l4 * 8;
        half8 a[4], b[4];
        for (int m = 0; m < 4; ++m) {
            int row = m * 16 + l15;
            a[m] = *reinterpret_cast<const half8*>(&xs[row * 256 + (k0 ^ ((row & 7) << 3))]);
        }
        for (int n = 0; n < 4; ++n)
            b[n] = *reinterpret_cast<const half8*>(w1t + (long)(ncol0 + n * 16) * 256 + k0);
        for (int m = 0; m < 4; ++m) for (int n = 0; n < 4; ++n)
            acc[m][n] = __builtin_amdgcn_mfma_f32_16x16x32_f16(a[m], b[n], acc[m][n], 0, 0, 0);
    }
    float b1v[4], w2v[4];
    for (int n = 0; n < 4; ++n) {
        int col = wv * 64 + n * 16 + l15;
        b1v[n] = b1[col]; w2v[n] = W2[col];
    }
    for (int m = 0; m < 4; ++m) {
        float s0 = 0, s1 = 0, s2 = 0, s3 = 0;
        for (int n = 0; n < 4; ++n) {
            float h0 = fmaxf(acc[m][n][0] + b1v[n], 0.f), h1 = fmaxf(acc[m][n][1] + b1v[n], 0.f);
            float h2 = fmaxf(acc[m][n][2] + b1v[n], 0.f), h3 = fmaxf(acc[m][n][3] + b1v[n], 0.f);
            s0 += h0 * w2v[n]; s1 += h1 * w2v[n]; s2 += h2 * w2v[n]; s3 += h3 * w2v[n];
        }
        for (int mask = 1; mask < 16; mask <<= 1) {
            s0 += __shfl_xor(s0, mask, 64); s1 += __shfl_xor(s1, mask, 64);
            s2 += __shfl_xor(s2, mask, 64); s3 += __shfl_xor(s3, mask, 64);
        }
        if (l15 == 0) {
            int rb = m * 16 + l4 * 4;
            partials[wv][rb] = s0; partials[wv][rb + 1] = s1;
            partials[wv][rb + 2] = s2; partials[wv][rb + 3] = s3;
        }
    }
    __syncthreads();
    if (tid < 64) {
        float p = partials[0][tid] + partials[1][tid] + partials[2][tid]
                + partials[3][tid] + b2[0];
        long e = eb0 + tid;
        if (e < NE) out[e] = 1.0f / (1.0f + expf(-p));
    }
}

extern "C" void kernel_launch(void* const* d_in, const int* in_sizes, int n_in,
                              void* d_out, int out_size, void* d_ws, size_t ws_size,
                              hipStream_t stream)
{
    const float* z  = (const float*)d_in[0];
    const float* z2 = (const float*)d_in[1];
    const int*  edge = (const int*)d_in[2];
    const float* W1 = (const float*)d_in[3];
    const float* b1 = (const float*)d_in[4];
    const float* W2 = (const float*)d_in[5];
    const float* b2 = (const float*)d_in[6];
    float* out = (float*)d_out;

    const size_t zh_bytes = (size_t)NNODES * ND * 2;         // 25.6 MB each
    const size_t need = 2 * zh_bytes + 256 * 256 * 2;        // + w1t
    const bool mirrors = (ws_size >= need);

    _Float16* zh  = (_Float16*)d_ws;
    _Float16* z2h = (_Float16*)((char*)d_ws + zh_bytes);
    _Float16* w1t = mirrors
        ? (_Float16*)((char*)d_ws + 2 * zh_bytes)
        : (_Float16*)d_ws;

    prep_w1t_kernel<<<256, 256, 0, stream>>>(W1, w1t);
    if (mirrors) {
        prep_zh_kernel<<<12500, 256, 0, stream>>>(z, z2, zh, z2h);
        const int nblk = (NT + TPB - 1) / TPB;   // 977
        edge_mlp_dma<<<nblk, 512, 0, stream>>>(
            zh, z2h, edge, w1t, b1, W2, b2, out);
    } else {
        edge_mlp_f32<<<NT, 256, 0, stream>>>(
            z, z2, edge, w1t, b1, W2, b2, out);
    }
}

// Round 8
// 162.336 us; speedup vs baseline: 1.1023x; 1.1023x over previous
//
#include <hip/hip_runtime.h>
#include <hip/hip_bf16.h>
#include <math.h>

typedef _Float16 half4 __attribute__((ext_vector_type(4)));
typedef _Float16 half8 __attribute__((ext_vector_type(8)));
typedef float f32x4 __attribute__((ext_vector_type(4)));

#define NE 500000
#define ND 128
#define NNODES 100000
#define NT ((NE + 63) / 64)          // 7813 tiles of 64 edges
#define TPB 8                        // tiles per block

// ---- prep: interleaved fp16 node mirror  zi[node][256] = [z row | z2 row] ----
__global__ __launch_bounds__(256) void prep_zi_kernel(
    const float* __restrict__ z, const float* __restrict__ z2,
    _Float16* __restrict__ zi) {
    long t = (long)blockIdx.x * 256 + threadIdx.x;      // 3.2M threads, 8 elems
    long idx = t * 8;
    if (idx >= (long)NNODES * 256) return;
    int node = (int)(idx >> 8), col = (int)(idx & 255);
    const float* src = (col < 128) ? (z + (long)node * 128 + col)
                                   : (z2 + (long)node * 128 + (col - 128));
    float4 a = *reinterpret_cast<const float4*>(src);
    float4 b = *reinterpret_cast<const float4*>(src + 4);
    half8 v;
    v[0] = (_Float16)a.x; v[1] = (_Float16)a.y;
    v[2] = (_Float16)a.z; v[3] = (_Float16)a.w;
    v[4] = (_Float16)b.x; v[5] = (_Float16)b.y;
    v[6] = (_Float16)b.z; v[7] = (_Float16)b.w;
    *reinterpret_cast<half8*>(zi + idx) = v;
}

// ---- prep: W1T fp16, PRE-SWIZZLED (16B-chunk ^ (col&7)) for LDS staging ----
// layout: w1s[col*256 + ((chunk ^ (col&7))*8 + (k&7))] = W1[k][col], chunk=k>>3
__global__ void prep_w1s_kernel(const float* __restrict__ W1,
                                _Float16* __restrict__ w1s) {
    int i = blockIdx.x * blockDim.x + threadIdx.x;   // 0..65535
    int col = i >> 8, k = i & 255;
    int kk = (((k >> 3) ^ (col & 7)) << 3) | (k & 7);
    w1s[col * 256 + kk] = (_Float16)W1[(long)k * 256 + col];
}

#define PUBLISH_BARRIER() do { \
    asm volatile("s_waitcnt lgkmcnt(0)" ::: "memory"); \
    __builtin_amdgcn_s_barrier(); \
    __builtin_amdgcn_sched_barrier(0); } while (0)

// v8: single-segment ordered gathers (dwordx2/lane of interleaved rows),
// W1T staged in LDS (128KB) once per block, partials alias the x-tile.
// Tile loop's only global ops: 16 gathers + 1 idx + 1 store (auto waitcnts).
__global__ __launch_bounds__(512, 1) void edge_mlp_v8(
    const _Float16* __restrict__ zi,
    const int* __restrict__ edge,
    const _Float16* __restrict__ w1s,
    const float* __restrict__ b1, const float* __restrict__ W2,
    const float* __restrict__ b2, float* __restrict__ out)
{
    __shared__ _Float16 w1lds[256 * 256];   // 128 KB, swizzled W1T
    __shared__ _Float16 xs[64 * 256];       // 32 KB, swizzled x-tile
    float* ps = (float*)xs;                 // partials[4][64] alias (1 KB)

    const int tid = threadIdx.x;
    const int lane = tid & 63;
    const int wv = tid >> 6;             // 0..7
    const int mi = wv >> 2;              // rows [mi*32, mi*32+32)
    const int ni = wv & 3;               // cols [ni*64, ni*64+64)
    const int l15 = lane & 15;
    const int l4 = lane >> 4;

    // ---- one-time: stage swizzled W1T into LDS (linear DMA) ----
    {
        const char* gsrc = (const char*)w1s + (long)(wv * 16) * 1024 + lane * 16;
        char* ldst = (char*)w1lds + (wv * 16) * 1024;   // wave-uniform base
#pragma unroll
        for (int i = 0; i < 16; ++i)
            __builtin_amdgcn_global_load_lds(
                (const void*)(gsrc + i * 1024), (void*)(ldst + i * 1024), 16, 0, 0);
    }

    // ---- loop-invariant epilogue params ----
    float b1v[4], w2v[4];
#pragma unroll
    for (int nf = 0; nf < 4; ++nf) {
        int col = ni * 64 + nf * 16 + l15;
        b1v[nf] = b1[col];
        w2v[nf] = W2[col];
    }
    const float bias2 = b2[0];

    const int t0 = blockIdx.x * TPB;
    const int tend = (t0 + TPB < NT) ? (t0 + TPB) : NT;

    half4 vs[8], vd[8];
    int idx_cur, idx_nxt;

#define LOAD_IDX(TT, DST) do {                                               \
        long tt_ = (TT); if (tt_ > NT - 1) tt_ = NT - 1;                     \
        long e_ = tt_ * 64 + wv * 8 + (lane & 7);                            \
        if (e_ >= NE) e_ = NE - 1;                                           \
        (DST) = edge[(((lane >> 3) & 1) ? (long)NE : 0L) + e_];              \
    } while (0)

    // each gather instr: 64 ordered lanes x 8B = ONE contiguous 512B node row
#define ISSUE_GATHER(IDXREG) do {                                            \
        _Pragma("unroll")                                                    \
        for (int j = 0; j < 8; ++j) {                                        \
            int s_ = __builtin_amdgcn_readlane((IDXREG), j);                 \
            int d_ = __builtin_amdgcn_readlane((IDXREG), 8 + j);             \
            vs[j] = *reinterpret_cast<const half4*>(zi + (long)s_ * 256 + lane * 4); \
            vd[j] = *reinterpret_cast<const half4*>(zi + (long)d_ * 256 + lane * 4); \
        }                                                                    \
    } while (0)

    // ---- prologue ----
    LOAD_IDX(t0, idx_cur);
    ISSUE_GATHER(idx_cur);            // gathers for t0 (after staging DMAs)
    LOAD_IDX(t0 + 1, idx_cur);        // indices for t1

    for (int t = t0; t < tend; ++t) {
        // (a) products -> swizzled x-tile rows [wv*8, wv*8+8)
#pragma unroll
        for (int j = 0; j < 8; ++j) {
            int e = wv * 8 + j;
            half4 p = vs[j] * vd[j];                       // 2x v_pk_mul_f16
            int boff = e * 512 + ((lane * 8) ^ ((e & 7) << 4));
            *reinterpret_cast<half4*>((char*)xs + boff) = p;
        }
        // (a2) prefetch gathers(t+1) + idx(t+2); in flight across MFMA
        if (t + 1 < tend) {
            ISSUE_GATHER(idx_cur);
            LOAD_IDX(t + 2, idx_nxt);
        }
        // (b) publish x-tile (lgkm only; gathers stay outstanding)
        PUBLISH_BARRIER();

        // (c) MFMA: A from xs, B from w1lds (both swizzled, <=2-way banks)
        f32x4 acc[2][4];
#pragma unroll
        for (int mf = 0; mf < 2; ++mf)
#pragma unroll
            for (int nf = 0; nf < 4; ++nf)
                acc[mf][nf] = (f32x4){0.f, 0.f, 0.f, 0.f};

#pragma unroll
        for (int ks = 0; ks < 8; ++ks) {
            const int kb = ks * 64 + l4 * 16;              // byte col offset
            half8 a[2], bfr[4];
#pragma unroll
            for (int mf = 0; mf < 2; ++mf) {
                int r = mi * 32 + mf * 16 + l15;
                a[mf] = *reinterpret_cast<const half8*>(
                    (const char*)xs + r * 512 + (kb ^ ((r & 7) << 4)));
            }
#pragma unroll
            for (int nf = 0; nf < 4; ++nf) {
                int c = ni * 64 + nf * 16 + l15;
                bfr[nf] = *reinterpret_cast<const half8*>(
                    (const char*)w1lds + c * 512 + (kb ^ ((c & 7) << 4)));
            }
#pragma unroll
            for (int mf = 0; mf < 2; ++mf)
#pragma unroll
                for (int nf = 0; nf < 4; ++nf)
                    acc[mf][nf] = __builtin_amdgcn_mfma_f32_16x16x32_f16(
                        a[mf], bfr[nf], acc[mf][nf], 0, 0, 0);
        }
        // (d) xs fully consumed by all waves
        PUBLISH_BARRIER();

        // (e) relu + dot(W2): 16-lane reduce -> partials (alias xs head)
#pragma unroll
        for (int mf = 0; mf < 2; ++mf) {
            float s0 = 0.f, s1 = 0.f, s2 = 0.f, s3 = 0.f;
#pragma unroll
            for (int nf = 0; nf < 4; ++nf) {
                float h0 = fmaxf(acc[mf][nf][0] + b1v[nf], 0.f);
                float h1 = fmaxf(acc[mf][nf][1] + b1v[nf], 0.f);
                float h2 = fmaxf(acc[mf][nf][2] + b1v[nf], 0.f);
                float h3 = fmaxf(acc[mf][nf][3] + b1v[nf], 0.f);
                s0 += h0 * w2v[nf]; s1 += h1 * w2v[nf];
                s2 += h2 * w2v[nf]; s3 += h3 * w2v[nf];
            }
#pragma unroll
            for (int mask = 1; mask < 16; mask <<= 1) {
                s0 += __shfl_xor(s0, mask, 64);
                s1 += __shfl_xor(s1, mask, 64);
                s2 += __shfl_xor(s2, mask, 64);
                s3 += __shfl_xor(s3, mask, 64);
            }
            if (l15 == 0) {
                int rb = mi * 32 + mf * 16 + l4 * 4;
                ps[ni * 64 + rb + 0] = s0;
                ps[ni * 64 + rb + 1] = s1;
                ps[ni * 64 + rb + 2] = s2;
                ps[ni * 64 + rb + 3] = s3;
            }
        }
        // (f) partials published
        PUBLISH_BARRIER();

        // (g) combine + sigmoid + store (each wave: its 8 edges)
        if (lane < 8) {
            int r = wv * 8 + lane;
            float p = ps[r] + ps[64 + r] + ps[128 + r] + ps[192 + r] + bias2;
            long e = (long)t * 64 + r;
            if (e < NE) out[e] = 1.0f / (1.0f + expf(-p));
        }
        idx_cur = idx_nxt;
        // (h) partials consumed; xs free for next tile
        PUBLISH_BARRIER();
    }
#undef LOAD_IDX
#undef ISSUE_GATHER
}

// Fallback (ws too small for zi mirror): f32 gather, w1s global swizzled reads
__global__ __launch_bounds__(256) void edge_mlp_f32(
    const float* __restrict__ z, const float* __restrict__ z2,
    const int* __restrict__ edge,
    const _Float16* __restrict__ w1s,
    const float* __restrict__ b1, const float* __restrict__ W2,
    const float* __restrict__ b2, float* __restrict__ out)
{
    __shared__ _Float16 xs[64 * 256];
    __shared__ float partials[4][64];
    const int tid = threadIdx.x, lane = tid & 63, wv = tid >> 6;
    const int l15 = lane & 15, l4 = lane >> 4;
    const long eb0 = (long)blockIdx.x * 64;
    {
        const int hz = lane >> 5, c4 = lane & 31;
        const float* base = hz ? z2 : z;
        for (int i = 0; i < 16; ++i) {
            int el = (wv << 4) + i;
            long ee = eb0 + el; if (ee >= NE) ee = NE - 1;
            long s = edge[ee], d = edge[NE + ee];
            float4 a = *reinterpret_cast<const float4*>(base + s * ND + (c4 << 2));
            float4 b = *reinterpret_cast<const float4*>(base + d * ND + (c4 << 2));
            int col0 = (hz << 7) + (c4 << 2);   // elem idx in row
            int boff = el * 512 + (((col0 * 2) & ~15) ^ ((el & 7) << 4)) + ((col0 * 2) & 15);
            _Float16* q = (_Float16*)((char*)xs + boff);
            q[0] = (_Float16)(a.x * b.x); q[1] = (_Float16)(a.y * b.y);
            q[2] = (_Float16)(a.z * b.z); q[3] = (_Float16)(a.w * b.w);
        }
    }
    __syncthreads();
    f32x4 acc[4][4];
    for (int m = 0; m < 4; ++m) for (int n = 0; n < 4; ++n) acc[m][n] = (f32x4){0,0,0,0};
    for (int ks = 0; ks < 8; ++ks) {
        const int kb = ks * 64 + l4 * 16;
        half8 a[4], b[4];
        for (int m = 0; m < 4; ++m) {
            int r = m * 16 + l15;
            a[m] = *reinterpret_cast<const half8*>((const char*)xs + r * 512 + (kb ^ ((r & 7) << 4)));
        }
        for (int n = 0; n < 4; ++n) {
            int c = wv * 64 + n * 16 + l15;
            b[n] = *reinterpret_cast<const half8*>((const char*)w1s + c * 512 + (kb ^ ((c & 7) << 4)));
        }
        for (int m = 0; m < 4; ++m) for (int n = 0; n < 4; ++n)
            acc[m][n] = __builtin_amdgcn_mfma_f32_16x16x32_f16(a[m], b[n], acc[m][n], 0, 0, 0);
    }
    float b1v[4], w2v[4];
    for (int n = 0; n < 4; ++n) {
        int col = wv * 64 + n * 16 + l15;
        b1v[n] = b1[col]; w2v[n] = W2[col];
    }
    for (int m = 0; m < 4; ++m) {
        float s0 = 0, s1 = 0, s2 = 0, s3 = 0;
        for (int n = 0; n < 4; ++n) {
            float h0 = fmaxf(acc[m][n][0] + b1v[n], 0.f), h1 = fmaxf(acc[m][n][1] + b1v[n], 0.f);
            float h2 = fmaxf(acc[m][n][2] + b1v[n], 0.f), h3 = fmaxf(acc[m][n][3] + b1v[n], 0.f);
            s0 += h0 * w2v[n]; s1 += h1 * w2v[n]; s2 += h2 * w2v[n]; s3 += h3 * w2v[n];
        }
        for (int mask = 1; mask < 16; mask <<= 1) {
            s0 += __shfl_xor(s0, mask, 64); s1 += __shfl_xor(s1, mask, 64);
            s2 += __shfl_xor(s2, mask, 64); s3 += __shfl_xor(s3, mask, 64);
        }
        if (l15 == 0) {
            int rb = m * 16 + l4 * 4;
            partials[wv][rb] = s0; partials[wv][rb + 1] = s1;
            partials[wv][rb + 2] = s2; partials[wv][rb + 3] = s3;
        }
    }
    __syncthreads();
    if (tid < 64) {
        float p = partials[0][tid] + partials[1][tid] + partials[2][tid]
                + partials[3][tid] + b2[0];
        long e = eb0 + tid;
        if (e < NE) out[e] = 1.0f / (1.0f + expf(-p));
    }
}

extern "C" void kernel_launch(void* const* d_in, const int* in_sizes, int n_in,
                              void* d_out, int out_size, void* d_ws, size_t ws_size,
                              hipStream_t stream)
{
    const float* z  = (const float*)d_in[0];
    const float* z2 = (const float*)d_in[1];
    const int*  edge = (const int*)d_in[2];
    const float* W1 = (const float*)d_in[3];
    const float* b1 = (const float*)d_in[4];
    const float* W2 = (const float*)d_in[5];
    const float* b2 = (const float*)d_in[6];
    float* out = (float*)d_out;

    const size_t zi_bytes = (size_t)NNODES * 256 * 2;        // 51.2 MB
    const size_t w1_bytes = 256 * 256 * 2;                   // 128 KB
    const bool mirrors = (ws_size >= zi_bytes + w1_bytes);

    _Float16* zi  = (_Float16*)d_ws;
    _Float16* w1s = mirrors ? (_Float16*)((char*)d_ws + zi_bytes)
                            : (_Float16*)d_ws;

    prep_w1s_kernel<<<256, 256, 0, stream>>>(W1, w1s);
    if (mirrors) {
        prep_zi_kernel<<<12500, 256, 0, stream>>>(z, z2, zi);
        const int nblk = (NT + TPB - 1) / TPB;   // 977
        edge_mlp_v8<<<nblk, 512, 0, stream>>>(
            zi, edge, w1s, b1, W2, b2, out);
    } else {
        edge_mlp_f32<<<NT, 256, 0, stream>>>(
            z, z2, edge, w1s, b1, W2, b2, out);
    }
}

// Round 9
// 139.150 us; speedup vs baseline: 1.2860x; 1.1666x over previous
//
#include <hip/hip_runtime.h>
#include <hip/hip_bf16.h>
#include <math.h>

typedef _Float16 half4 __attribute__((ext_vector_type(4)));
typedef _Float16 half8 __attribute__((ext_vector_type(8)));
typedef float f32x4 __attribute__((ext_vector_type(4)));

#define NE 500000
#define ND 128
#define NNODES 100000
#define NT ((NE + 63) / 64)          // 7813 tiles of 64 edges

// ---- prep: interleaved fp16 node mirror  zi[node][256] = [z row | z2 row] ----
__global__ __launch_bounds__(256) void prep_zi_kernel(
    const float* __restrict__ z, const float* __restrict__ z2,
    _Float16* __restrict__ zi) {
    long t = (long)blockIdx.x * 256 + threadIdx.x;      // 3.2M threads, 8 elems
    long idx = t * 8;
    if (idx >= (long)NNODES * 256) return;
    int node = (int)(idx >> 8), col = (int)(idx & 255);
    const float* src = (col < 128) ? (z + (long)node * 128 + col)
                                   : (z2 + (long)node * 128 + (col - 128));
    float4 a = *reinterpret_cast<const float4*>(src);
    float4 b = *reinterpret_cast<const float4*>(src + 4);
    half8 v;
    v[0] = (_Float16)a.x; v[1] = (_Float16)a.y;
    v[2] = (_Float16)a.z; v[3] = (_Float16)a.w;
    v[4] = (_Float16)b.x; v[5] = (_Float16)b.y;
    v[6] = (_Float16)b.z; v[7] = (_Float16)b.w;
    *reinterpret_cast<half8*>(zi + idx) = v;
}

// ---- prep: W1 packed into MFMA B-fragment order ----
// w1p half-index i = ni*16384 + nf*4096 + ks*512 + lane*8 + j
//   holds W1[k][col] with col = ni*64+nf*16+(lane&15), k = ks*32+(lane>>4)*8+j.
// In-kernel B-frag load = w1p + (ni*32+nf*8+ks)*512 + lane*8 : one linear 1KB
// segment per wave instruction (L2-resident, zero scatter).
__global__ void prep_w1p_kernel(const float* __restrict__ W1,
                                _Float16* __restrict__ w1p) {
    int i = blockIdx.x * blockDim.x + threadIdx.x;   // 0..65535
    int j = i & 7;
    int lane = (i >> 3) & 63;
    int ks = (i >> 9) & 7;
    int nf = (i >> 12) & 3;
    int ni = i >> 14;
    int col = ni * 64 + nf * 16 + (lane & 15);
    int k = ks * 32 + (lane >> 4) * 8 + j;
    w1p[i] = (_Float16)W1[(long)k * 256 + col];
}

// v9: occupancy-first. 256 threads / 4 waves, 1 tile per block, LDS = 33KB
// -> 4 blocks/CU (16 waves). Wave wv owns cols [wv*64, wv*64+64), all rows.
// No manual pipelining: TLP hides gather latency. B-frags from L2 (packed).
template<int MIRROR>
__global__ __launch_bounds__(256, 4) void edge_mlp_v9(
    const float* __restrict__ z, const float* __restrict__ z2,
    const _Float16* __restrict__ zi,
    const int* __restrict__ edge,
    const _Float16* __restrict__ w1p,
    const float* __restrict__ b1, const float* __restrict__ W2,
    const float* __restrict__ b2, float* __restrict__ out)
{
    __shared__ _Float16 xs[64 * 256];   // 32 KB, XOR-swizzled x-tile
    __shared__ float ps[256];           // 1 KB partials [ni][row]

    const int tid = threadIdx.x;
    const int lane = tid & 63;
    const int wv = tid >> 6;            // 0..3 == ni (col quarter)
    const int l15 = lane & 15;
    const int l4 = lane >> 4;
    const long eb0 = (long)blockIdx.x * 64;

    // wave's 16 edges: lanes 0-15 carry src idx, lanes 16-31 dst idx
    int idx;
    {
        long e = eb0 + wv * 16 + l15; if (e >= NE) e = NE - 1;
        idx = edge[(((lane >> 4) & 1) ? (long)NE : 0L) + e];
    }

    // loop-invariant epilogue params (issued early, used late)
    float b1v[4], w2v[4];
#pragma unroll
    for (int nf = 0; nf < 4; ++nf) {
        int col = wv * 64 + nf * 16 + l15;
        b1v[nf] = b1[col];
        w2v[nf] = W2[col];
    }
    const float bias2 = b2[0];

    // ---- gather + product -> swizzled x-tile rows [wv*16, wv*16+16) ----
    if (MIRROR) {
        half4 vs[8], vd[8];
#pragma unroll
        for (int b = 0; b < 2; ++b) {
#pragma unroll
            for (int j = 0; j < 8; ++j) {
                int s = __builtin_amdgcn_readlane(idx, b * 8 + j);
                int d = __builtin_amdgcn_readlane(idx, 16 + b * 8 + j);
                // one instr = one contiguous 512B node row (64 lanes x 8B)
                vs[j] = *reinterpret_cast<const half4*>(zi + (long)s * 256 + lane * 4);
                vd[j] = *reinterpret_cast<const half4*>(zi + (long)d * 256 + lane * 4);
            }
#pragma unroll
            for (int j = 0; j < 8; ++j) {
                int e = wv * 16 + b * 8 + j;
                half4 p = vs[j] * vd[j];                  // 2x v_pk_mul_f16
                *reinterpret_cast<half4*>(
                    (char*)xs + e * 512 + ((lane * 8) ^ ((e & 7) << 4))) = p;
            }
        }
    } else {
        const float* zs = (lane < 32) ? z : z2;
        const int coff = (lane & 31) * 4;
#pragma unroll
        for (int b = 0; b < 4; ++b) {
            float4 fs[4], fd[4];
#pragma unroll
            for (int j = 0; j < 4; ++j) {
                int s = __builtin_amdgcn_readlane(idx, b * 4 + j);
                int d = __builtin_amdgcn_readlane(idx, 16 + b * 4 + j);
                fs[j] = *reinterpret_cast<const float4*>(zs + (long)s * ND + coff);
                fd[j] = *reinterpret_cast<const float4*>(zs + (long)d * ND + coff);
            }
#pragma unroll
            for (int j = 0; j < 4; ++j) {
                int e = wv * 16 + b * 4 + j;
                half4 p;
                p[0] = (_Float16)(fs[j].x * fd[j].x);
                p[1] = (_Float16)(fs[j].y * fd[j].y);
                p[2] = (_Float16)(fs[j].z * fd[j].z);
                p[3] = (_Float16)(fs[j].w * fd[j].w);
                *reinterpret_cast<half4*>(
                    (char*)xs + e * 512 + ((lane * 8) ^ ((e & 7) << 4))) = p;
            }
        }
    }
    __syncthreads();

    // ---- MFMA: A (all 64 rows) from LDS, B (64-col quarter) from L2 ----
    f32x4 acc[4][4];
#pragma unroll
    for (int mf = 0; mf < 4; ++mf)
#pragma unroll
        for (int nf = 0; nf < 4; ++nf)
            acc[mf][nf] = (f32x4){0.f, 0.f, 0.f, 0.f};

#pragma unroll
    for (int ks = 0; ks < 8; ++ks) {
        const int kb = ks * 64 + l4 * 16;               // byte col offset
        half8 a[4], bfr[4];
#pragma unroll
        for (int mf = 0; mf < 4; ++mf) {
            int r = mf * 16 + l15;
            a[mf] = *reinterpret_cast<const half8*>(
                (const char*)xs + r * 512 + (kb ^ ((r & 7) << 4)));
        }
#pragma unroll
        for (int nf = 0; nf < 4; ++nf)
            bfr[nf] = *reinterpret_cast<const half8*>(
                w1p + (wv * 32 + nf * 8 + ks) * 512 + lane * 8);
#pragma unroll
        for (int mf = 0; mf < 4; ++mf)
#pragma unroll
            for (int nf = 0; nf < 4; ++nf)
                acc[mf][nf] = __builtin_amdgcn_mfma_f32_16x16x32_f16(
                    a[mf], bfr[nf], acc[mf][nf], 0, 0, 0);
    }
    __syncthreads();   // xs consumed (ps does not alias, but keep order clean)

    // ---- relu + dot(W2): 16-lane shuffle reduce -> partials ----
#pragma unroll
    for (int mf = 0; mf < 4; ++mf) {
        float s0 = 0.f, s1 = 0.f, s2 = 0.f, s3 = 0.f;
#pragma unroll
        for (int nf = 0; nf < 4; ++nf) {
            float h0 = fmaxf(acc[mf][nf][0] + b1v[nf], 0.f);
            float h1 = fmaxf(acc[mf][nf][1] + b1v[nf], 0.f);
            float h2 = fmaxf(acc[mf][nf][2] + b1v[nf], 0.f);
            float h3 = fmaxf(acc[mf][nf][3] + b1v[nf], 0.f);
            s0 += h0 * w2v[nf]; s1 += h1 * w2v[nf];
            s2 += h2 * w2v[nf]; s3 += h3 * w2v[nf];
        }
#pragma unroll
        for (int mask = 1; mask < 16; mask <<= 1) {
            s0 += __shfl_xor(s0, mask, 64);
            s1 += __shfl_xor(s1, mask, 64);
            s2 += __shfl_xor(s2, mask, 64);
            s3 += __shfl_xor(s3, mask, 64);
        }
        if (l15 == 0) {
            int rb = mf * 16 + l4 * 4;
            ps[wv * 64 + rb + 0] = s0;
            ps[wv * 64 + rb + 1] = s1;
            ps[wv * 64 + rb + 2] = s2;
            ps[wv * 64 + rb + 3] = s3;
        }
    }
    __syncthreads();

    // ---- combine + sigmoid + store ----
    if (tid < 64) {
        float p = ps[tid] + ps[64 + tid] + ps[128 + tid] + ps[192 + tid] + bias2;
        long e = eb0 + tid;
        if (e < NE) out[e] = 1.0f / (1.0f + expf(-p));
    }
}

extern "C" void kernel_launch(void* const* d_in, const int* in_sizes, int n_in,
                              void* d_out, int out_size, void* d_ws, size_t ws_size,
                              hipStream_t stream)
{
    const float* z  = (const float*)d_in[0];
    const float* z2 = (const float*)d_in[1];
    const int*  edge = (const int*)d_in[2];
    const float* W1 = (const float*)d_in[3];
    const float* b1 = (const float*)d_in[4];
    const float* W2 = (const float*)d_in[5];
    const float* b2 = (const float*)d_in[6];
    float* out = (float*)d_out;

    const size_t zi_bytes = (size_t)NNODES * 256 * 2;        // 51.2 MB
    const size_t w1_bytes = 256 * 256 * 2;                   // 128 KB
    const bool mirrors = (ws_size >= zi_bytes + w1_bytes);

    _Float16* zi  = (_Float16*)d_ws;
    _Float16* w1p = mirrors ? (_Float16*)((char*)d_ws + zi_bytes)
                            : (_Float16*)d_ws;

    prep_w1p_kernel<<<256, 256, 0, stream>>>(W1, w1p);
    if (mirrors) {
        prep_zi_kernel<<<12500, 256, 0, stream>>>(z, z2, zi);
        edge_mlp_v9<1><<<NT, 256, 0, stream>>>(
            z, z2, zi, edge, w1p, b1, W2, b2, out);
    } else {
        edge_mlp_v9<0><<<NT, 256, 0, stream>>>(
            z, z2, (const _Float16*)nullptr, edge, w1p, b1, W2, b2, out);
    }
}